// Round 3
// baseline (622.423 us; speedup 1.0000x reference)
//
#include <hip/hip_runtime.h>

// NoiseMemoryBank: per-sample random row gather from a [1000, 512, 256] f32 bank.
//   cnt = counts[id]; idx = rand_idx % max(cnt,1);
//   out = cnt>0 ? bank[id, idx] : fallback_noise[sample]
//
// Layout: one wave (64 lanes) per sample. One row = 256 f32 = 1024 B
// = 64 lanes x 16B -> one fully-coalesced 1 KB load + 1 KB store per wave.
// Output is write-once/never-read: non-temporal stores keep L3 for bank rows
// (graph replays reuse the same rows, so L3 retention cuts FETCH_SIZE).
//
// Note: __builtin_nontemporal_store needs a clang vector type, not HIP's
// float4 class -> use ext_vector_type(4).

typedef float f32x4 __attribute__((ext_vector_type(4)));

#define FEAT_DIM   256
#define CAPACITY   512
#define WAVES_PER_BLOCK 4   // 256 threads

__global__ __launch_bounds__(256) void noise_bank_gather(
    const int* __restrict__ target_center_ids,
    const int* __restrict__ rand_idx,
    const int* __restrict__ counts,
    const float* __restrict__ bank,
    const float* __restrict__ fallback_noise,
    float* __restrict__ out,
    int batch)
{
    const int wave_in_block = threadIdx.x >> 6;          // 0..3
    const int lane          = threadIdx.x & 63;          // 0..63
    const int sample        = blockIdx.x * WAVES_PER_BLOCK + wave_in_block;
    if (sample >= batch) return;

    // Wave-uniform scalar metadata (all lanes hit the same address -> broadcast).
    const int id  = target_center_ids[sample];
    const int cnt = counts[id];
    const int ri  = rand_idx[sample];
    const int safe_cnt = cnt > 0 ? cnt : 1;
    const int idx = ri % safe_cnt;                       // uniform-ish in [0, cnt)

    // Source row: bank[id, idx, :] if cnt>0 else fallback_noise[sample, :].
    const f32x4* src;
    if (cnt > 0) {
        src = reinterpret_cast<const f32x4*>(
            bank + ((size_t)id * CAPACITY + (size_t)idx) * FEAT_DIM);
    } else {
        src = reinterpret_cast<const f32x4*>(
            fallback_noise + (size_t)sample * FEAT_DIM);
    }

    f32x4* dst = reinterpret_cast<f32x4*>(out + (size_t)sample * FEAT_DIM);

    // 256 floats = 64 x 16B: one per lane. Non-temporal store: output is
    // never re-read, keep L3 for the bank.
    __builtin_nontemporal_store(src[lane], dst + lane);
}

extern "C" void kernel_launch(void* const* d_in, const int* in_sizes, int n_in,
                              void* d_out, int out_size, void* d_ws, size_t ws_size,
                              hipStream_t stream) {
    const int*   target_center_ids = (const int*)d_in[0];
    const int*   rand_idx          = (const int*)d_in[1];
    const int*   counts            = (const int*)d_in[2];
    const float* bank              = (const float*)d_in[3];
    const float* fallback_noise    = (const float*)d_in[4];
    float*       out               = (float*)d_out;

    const int batch = in_sizes[0];                       // 65536
    const int blocks = (batch + WAVES_PER_BLOCK - 1) / WAVES_PER_BLOCK;

    noise_bank_gather<<<blocks, 256, 0, stream>>>(
        target_center_ids, rand_idx, counts, bank, fallback_noise, out, batch);
}